// Round 14
// baseline (27.962 us; speedup 1.0000x reference)
//
#include <hip/hip_runtime.h>
#include <hip/hip_fp16.h>

// ============================================================================
// PC-DONN collapse (validated rounds 1-13, absmax 0.0):
//   |H|==1 and |exp(i*phase)|==1; FFT pairs obey Parseval => sum|field|^2 is
//   exactly invariant through the whole propagation chain. Hence
//       out[b] = (1/M) * sum_p x_in[b,p]^2 * sum_m |T_m[p]|^2
//   with T_m = fftshift(IDFT2_unnorm(C_m * G)), G = sqrt(p_v + 1e-12).
//
// Round 14: R13 falsified block-shape (clone K2 ~ R10). Recalibrated model:
// kernels are near floor (K1~5, K2~4, K3~2.5) and the residual ~12us is
// INTER-NODE overhead ~4.5us/node (R12: +1 node of ~1us work cost +6.5us).
// Cut 3 nodes -> 2: fuse the batch-dot into K2 from validated pieces --
// R10's MG=2 colfft, R6/R7's verified Wt[sr][q] + wave-per-batch coalesced
// x-dot, and R5's proven-benign single 32-lane coalesced atomicAdd per
// block into out[0..31] (R7's disaster was single-LANE atomics; R5/here:
// one coalesced instruction per block, 400 total). K1 zeroes out[] each
// call. Predict 25.3 -> ~19-21; if ~24-25, node-overhead theory is wrong.
// ============================================================================

struct cplx { float x, y; };
__device__ __forceinline__ cplx cadd(cplx a, cplx b){ return {a.x+b.x, a.y+b.y}; }
__device__ __forceinline__ cplx csub(cplx a, cplx b){ return {a.x-b.x, a.y-b.y}; }
__device__ __forceinline__ cplx cmul(cplx a, cplx b){ return {a.x*b.x - a.y*b.y, a.x*b.y + a.y*b.x}; }
__device__ __forceinline__ cplx cmuli(cplx a){ return {-a.y, a.x}; }   // * (+i): inverse-FFT sign

__device__ __forceinline__ void idft4(cplx&A,cplx&B,cplx&C,cplx&D){
    cplx e0=cadd(A,C), e1=csub(A,C), o0=cadd(B,D), o1=csub(B,D);
    cplx i1 = cmuli(o1);
    A=cadd(e0,o0); B=cadd(e1,i1); C=csub(e0,o0); D=csub(e1,i1);
}
__device__ __forceinline__ void idft8(cplx a[8]){
    cplx e0=a[0],e1=a[2],e2=a[4],e3=a[6];
    cplx o0=a[1],o1=a[3],o2=a[5],o3=a[7];
    idft4(e0,e1,e2,e3); idft4(o0,o1,o2,o3);
    const float Ch = 0.70710678118654752f;
    cplx t1 = cmul(o1, cplx{ Ch, Ch});
    cplx t2 = cmuli(o2);
    cplx t3 = cmul(o3, cplx{-Ch, Ch});
    a[0]=cadd(e0,o0); a[4]=csub(e0,o0);
    a[1]=cadd(e1,t1); a[5]=csub(e1,t1);
    a[2]=cadd(e2,t2); a[6]=csub(e2,t2);
    a[3]=cadd(e3,t3); a[7]=csub(e3,t3);
}
__device__ __forceinline__ void idft16(cplx a[16]){
    cplx e[8]={a[0],a[2],a[4],a[6],a[8],a[10],a[12],a[14]};
    cplx o[8]={a[1],a[3],a[5],a[7],a[9],a[11],a[13],a[15]};
    idft8(e); idft8(o);
    const float Ch=0.70710678118654752f, c1=0.92387953251128674f, s1=0.38268343236508977f;
    const cplx w[8]={{1.f,0.f},{c1,s1},{Ch,Ch},{s1,c1},{0.f,1.f},{-s1,c1},{-Ch,Ch},{-c1,s1}};
    #pragma unroll
    for(int n=0;n<8;++n){ cplx t=cmul(o[n],w[n]); a[n]=cadd(e[n],t); a[n+8]=csub(e[n],t); }
}

#define LDSP 130   // padded row stride (cplx)
#define NR   16    // rows (or cols) per tile
#define MG   2     // screens per K2 block (concurrent sub-groups; M%MG==0)

// In-place FFT-128 of (blockDim.x/8) rows in fld. r=tid>>3 row, t=tid&7.
__device__ __forceinline__ void fft128_rows(cplx* fld, const cplx* tw, int tid)
{
    const int r = tid >> 3, t = tid & 7;
    cplx* row = fld + r * LDSP;
    {   cplx a[16];
        #pragma unroll
        for (int k1 = 0; k1 < 16; ++k1) a[k1] = row[t + 8*k1];
        idft16(a);
        #pragma unroll
        for (int n1 = 0; n1 < 16; ++n1) row[t + 8*n1] = cmul(a[n1], tw[(n1*t) & 127]);
    }
    __syncthreads();
    {   cplx b0[8], b1[8];
        #pragma unroll
        for (int k2 = 0; k2 < 8; ++k2) { b0[k2] = row[8*t + k2]; b1[k2] = row[8*(t+8) + k2]; }
        idft8(b0); idft8(b1);
        __syncthreads();
        #pragma unroll
        for (int n2 = 0; n2 < 8; ++n2) {
            row[ t      + 16*n2] = b0[n2];
            row[(t + 8) + 16*n2] = b1[n2];
        }
    }
    __syncthreads();
}

__device__ __forceinline__ unsigned h2_to_u(__half2 h){
    union { __half2 h; unsigned u; } v; v.h = h; return v.u;
}

// K1: row FFTs of C*G -> transposed fp16 mid[m][c*128 + i]; block (0,0)
// zeroes out[] (replay-safe accumulation base for K2's atomics).
__global__ __launch_bounds__(128)
void rowfft_kernel(const float* __restrict__ c_noise, __half2* __restrict__ mid,
                   float* __restrict__ out, int B)
{
    __shared__ cplx fld[NR * LDSP];
    __shared__ cplx tw[128];
    const int m   = blockIdx.x;
    const int rb  = blockIdx.y * NR;
    const int tid = threadIdx.x;

    if (m == 0 && blockIdx.y == 0 && tid < B) out[tid] = 0.f;

    {   float s, c;
        sincosf((float)tid * (float)(2.0 * M_PI / 128.0), &s, &c);
        tw[tid] = { c, s };
    }

    const float DF = 976.5625f;                  // 1/(N*DX)
    const float Ac = 2.5132741228718345e-7f;     // 2*pi*L^2
    const float Bc = 7.8956835208714865e-7f;     // 2*pi^2*L^2
    #pragma unroll
    for (int it = 0; it < NR; ++it) {
        const int i = rb + it, j = tid;
        float fi = (float)(((i+64)&127) - 64) * DF;
        float fj = (float)(((j+64)&127) - 64) * DF;
        float G  = sqrtf(Ac * expf(-Bc * (fi*fi + fj*fj)) + 1e-12f);
        float2 cv = ((const float2*)c_noise)[(size_t)m*16384 + i*128 + j];
        fld[it*LDSP + j] = { cv.x * G, cv.y * G };
    }
    __syncthreads();

    fft128_rows(fld, tw, tid);

    // transposed fp16 store: thread = column c; 16 rows = 64 B = 4 x uint4
    const int c = tid;
    uint4* dst4 = (uint4*)(mid + (size_t)m*16384 + (size_t)c*128 + rb);
    #pragma unroll
    for (int q = 0; q < 4; ++q) {
        uint4 pk;
        cplx v0 = fld[(4*q+0)*LDSP + c];
        cplx v1 = fld[(4*q+1)*LDSP + c];
        cplx v2 = fld[(4*q+2)*LDSP + c];
        cplx v3 = fld[(4*q+3)*LDSP + c];
        pk.x = h2_to_u(__floats2half2_rn(v0.x, v0.y));
        pk.y = h2_to_u(__floats2half2_rn(v1.x, v1.y));
        pk.z = h2_to_u(__floats2half2_rn(v2.x, v2.y));
        pk.w = h2_to_u(__floats2half2_rn(v3.x, v3.y));
        dst4[q] = pk;
    }
}

// K2: 2 screens concurrently; col FFT; |T|^2 -> Wt[sr][q] (shift folded,
// R7-verified layout); wave-per-batch coalesced dot vs x^2 (R6/R8 pattern);
// ONE 32-lane coalesced atomicAdd per block into out[0..31] (R5 pattern).
__global__ __launch_bounds__(256)
void colfft_dot_kernel(const __half2* __restrict__ mid,
                       const float* __restrict__ x,
                       float* __restrict__ out, int M, int B)
{
    __shared__ cplx  fld[MG * NR * LDSP];     // 2 slabs of 16 rows -> 33.3 KB
    __shared__ cplx  tw[128];
    __shared__ float Wt[128 * NR];            // [shifted_row][col-offset 0..15]
    __shared__ float sums[32];
    const int g   = blockIdx.x;               // screen pair
    const int cb  = blockIdx.y * NR;          // column tile base (16-aligned)
    const int tid = threadIdx.x;
    const int grp = tid >> 7;                 // screen sub-group 0..1
    const int lt  = tid & 127;                // lane within sub-group

    if (tid < 128) {
        float s, c;
        sincosf((float)tid * (float)(2.0 * M_PI / 128.0), &s, &c);
        tw[tid] = { c, s };
    }

    // load: sub-group grp loads screen m's 16-column tile (fp16 -> f32)
    {
        const int m = g*MG + grp;             // M % MG == 0
        #pragma unroll
        for (int it = 0; it < NR; ++it) {
            float2 v = __half22float2(mid[(size_t)m*16384 + (size_t)(cb + it)*128 + lt]);
            fld[(grp*NR + it)*LDSP + lt] = { v.x, v.y };
        }
    }
    __syncthreads();

    fft128_rows(fld, tw, tid);                // 32 rows across both slabs

    // |T|^2 in place (as .x)
    #pragma unroll
    for (int it = 0; it < NR; ++it) {
        cplx v = fld[(grp*NR + it)*LDSP + lt];
        fld[(grp*NR + it)*LDSP + lt].x = v.x*v.x + v.y*v.y;
    }
    __syncthreads();

    // reduce 2 slabs -> Wt[sr*16 + q], folding fftshift on the row axis
    // (sr = physical_row ^ 64; column shift via c0 below). R7-verified.
    #pragma unroll
    for (int k = 0; k < 8; ++k) {
        int p  = k*256 + tid;                 // 0..2047
        int sr = p >> 4, q = p & 15;
        int pr = sr ^ 64;
        Wt[p] = fld[(     q)*LDSP + pr].x + fld[(NR + q)*LDSP + pr].x;
    }
    __syncthreads();

    // dot vs x^2 -- wave-per-batch, coalesced float4 x loads (R6/R8).
    // lane: qq = lane&3 (col quad), rsub = lane>>2 (row-in-16). Wave w
    // completes batch b = pass*4 + w; lane 0 deposits into sums[b].
    const int c0   = cb ^ 64;                 // shifted column base
    const int w    = tid >> 6, lane = tid & 63;
    const int qq   = lane & 3, rsub = lane >> 2;
    const float4* Wt4 = (const float4*)Wt;

    #pragma unroll
    for (int pass = 0; pass < 8; ++pass) {
        const int b = pass*4 + w;             // 0..31
        float sv = 0.f;
        #pragma unroll
        for (int it8 = 0; it8 < 8; ++it8) {
            const int sr = it8*16 + rsub;
            float4 xv = *(const float4*)(x + (size_t)b*16384 + sr*128 + c0 + 4*qq);
            float4 wv = Wt4[sr*4 + qq];
            sv = fmaf(xv.x*xv.x, wv.x, sv);
            sv = fmaf(xv.y*xv.y, wv.y, sv);
            sv = fmaf(xv.z*xv.z, wv.z, sv);
            sv = fmaf(xv.w*xv.w, wv.w, sv);
        }
        #pragma unroll
        for (int off = 32; off > 0; off >>= 1) sv += __shfl_down(sv, off);
        if (lane == 0) sums[b] = sv;
    }
    __syncthreads();

    // one coalesced 32-lane atomic instruction per block (R5 pattern)
    if (tid < B && tid < 32)
        atomicAdd(&out[tid], sums[tid] / (float)M);
}

extern "C" void kernel_launch(void* const* d_in, const int* in_sizes, int n_in,
                              void* d_out, int out_size, void* d_ws, size_t ws_size,
                              hipStream_t stream)
{
    (void)n_in; (void)ws_size;
    const float* x_in    = (const float*)d_in[0];
    // d_in[1] (phases) provably does not affect the output (|exp(i*phase)|=1).
    const float* c_noise = (const float*)d_in[2];

    const int M = in_sizes[2] / (128*128*2);   // 100 (M % MG == 0)
    const int B = out_size;                    // 32

    __half2* mid = (__half2*)d_ws;             // 6.55 MB

    const int G = M / MG;                      // 50 screen pairs

    rowfft_kernel    <<<dim3(M, 8), dim3(128), 0, stream>>>(c_noise, mid,
                                                            (float*)d_out, B);
    colfft_dot_kernel<<<dim3(G, 8), dim3(256), 0, stream>>>(mid, x_in,
                                                            (float*)d_out, M, B);
}

// Round 15
// 22.816 us; speedup vs baseline: 1.2255x; 1.2255x over previous
//
#include <hip/hip_runtime.h>
#include <hip/hip_fp16.h>

// ============================================================================
// PC-DONN collapse (validated rounds 1-14, absmax 0.0):
//   |H|==1 and |exp(i*phase)|==1; FFT pairs obey Parseval => sum|field|^2 is
//   exactly invariant through the whole propagation chain. Hence
//       out[b] = (1/M) * sum_p x_in[b,p]^2 * sum_m |T_m[p]|^2
//   with T_m = fftshift(IDFT2_unnorm(C_m * G)), G = sqrt(p_v + 1e-12).
//
// Round 15: R14 (2-node fused dot) = 28.0 > R10's 24.2 -- node gap is ~2us,
// not 4.5, and the dot must stay in its own kernel (x read once, not per
// tile). R10 = empirical optimum {K1 rowFFT, K2 colFFT+scattered-atomics,
// K3 dot}. Only K3 is visibly above floor: 32 blocks x 4 waves = 32 CUs,
// latency-bound (~3.5us for 0.4us of traffic). Single change vs R10:
// K3 widened to 1024 threads (16 waves/block, 4x outstanding loads).
// K1/K2 byte-identical to R10. Predict 24.2 -> ~22-23.5; if ~24 (noise),
// we are at the structural floor (fixed ~10us replay overhead + kernels
// at latency floor) -> declare roofline.
// ============================================================================

struct cplx { float x, y; };
__device__ __forceinline__ cplx cadd(cplx a, cplx b){ return {a.x+b.x, a.y+b.y}; }
__device__ __forceinline__ cplx csub(cplx a, cplx b){ return {a.x-b.x, a.y-b.y}; }
__device__ __forceinline__ cplx cmul(cplx a, cplx b){ return {a.x*b.x - a.y*b.y, a.x*b.y + a.y*b.x}; }
__device__ __forceinline__ cplx cmuli(cplx a){ return {-a.y, a.x}; }   // * (+i): inverse-FFT sign

__device__ __forceinline__ void idft4(cplx&A,cplx&B,cplx&C,cplx&D){
    cplx e0=cadd(A,C), e1=csub(A,C), o0=cadd(B,D), o1=csub(B,D);
    cplx i1 = cmuli(o1);
    A=cadd(e0,o0); B=cadd(e1,i1); C=csub(e0,o0); D=csub(e1,i1);
}
__device__ __forceinline__ void idft8(cplx a[8]){
    cplx e0=a[0],e1=a[2],e2=a[4],e3=a[6];
    cplx o0=a[1],o1=a[3],o2=a[5],o3=a[7];
    idft4(e0,e1,e2,e3); idft4(o0,o1,o2,o3);
    const float Ch = 0.70710678118654752f;
    cplx t1 = cmul(o1, cplx{ Ch, Ch});
    cplx t2 = cmuli(o2);
    cplx t3 = cmul(o3, cplx{-Ch, Ch});
    a[0]=cadd(e0,o0); a[4]=csub(e0,o0);
    a[1]=cadd(e1,t1); a[5]=csub(e1,t1);
    a[2]=cadd(e2,t2); a[6]=csub(e2,t2);
    a[3]=cadd(e3,t3); a[7]=csub(e3,t3);
}
__device__ __forceinline__ void idft16(cplx a[16]){
    cplx e[8]={a[0],a[2],a[4],a[6],a[8],a[10],a[12],a[14]};
    cplx o[8]={a[1],a[3],a[5],a[7],a[9],a[11],a[13],a[15]};
    idft8(e); idft8(o);
    const float Ch=0.70710678118654752f, c1=0.92387953251128674f, s1=0.38268343236508977f;
    const cplx w[8]={{1.f,0.f},{c1,s1},{Ch,Ch},{s1,c1},{0.f,1.f},{-s1,c1},{-Ch,Ch},{-c1,s1}};
    #pragma unroll
    for(int n=0;n<8;++n){ cplx t=cmul(o[n],w[n]); a[n]=cadd(e[n],t); a[n+8]=csub(e[n],t); }
}

#define LDSP 130   // padded row stride (cplx)
#define NR   16    // rows (or cols) per tile
#define MG   2     // screens per K2 block (concurrent sub-groups; M%MG==0)

// In-place FFT-128 of (blockDim.x/8) rows in fld. r=tid>>3 row, t=tid&7.
__device__ __forceinline__ void fft128_rows(cplx* fld, const cplx* tw, int tid)
{
    const int r = tid >> 3, t = tid & 7;
    cplx* row = fld + r * LDSP;
    {   cplx a[16];
        #pragma unroll
        for (int k1 = 0; k1 < 16; ++k1) a[k1] = row[t + 8*k1];
        idft16(a);
        #pragma unroll
        for (int n1 = 0; n1 < 16; ++n1) row[t + 8*n1] = cmul(a[n1], tw[(n1*t) & 127]);
    }
    __syncthreads();
    {   cplx b0[8], b1[8];
        #pragma unroll
        for (int k2 = 0; k2 < 8; ++k2) { b0[k2] = row[8*t + k2]; b1[k2] = row[8*(t+8) + k2]; }
        idft8(b0); idft8(b1);
        __syncthreads();
        #pragma unroll
        for (int n2 = 0; n2 < 8; ++n2) {
            row[ t      + 16*n2] = b0[n2];
            row[(t + 8) + 16*n2] = b1[n2];
        }
    }
    __syncthreads();
}

__device__ __forceinline__ unsigned h2_to_u(__half2 h){
    union { __half2 h; unsigned u; } v; v.h = h; return v.u;
}

// K1: row FFTs of C*G -> transposed fp16 mid[m][c*128 + i]; m==0 blocks
// also zero Wsh (replay-safe accumulation base).
__global__ __launch_bounds__(128)
void rowfft_kernel(const float* __restrict__ c_noise, __half2* __restrict__ mid,
                   float* __restrict__ Wsh)
{
    __shared__ cplx fld[NR * LDSP];
    __shared__ cplx tw[128];
    const int m   = blockIdx.x;
    const int rb  = blockIdx.y * NR;
    const int tid = threadIdx.x;

    if (m == 0) {                       // zero Wsh: 8 blocks x 2048 floats
        float4* wz = (float4*)Wsh;
        #pragma unroll
        for (int k = 0; k < 4; ++k)
            wz[blockIdx.y*512 + k*128 + tid] = {0.f, 0.f, 0.f, 0.f};
    }

    {   float s, c;
        sincosf((float)tid * (float)(2.0 * M_PI / 128.0), &s, &c);
        tw[tid] = { c, s };
    }

    const float DF = 976.5625f;                  // 1/(N*DX)
    const float Ac = 2.5132741228718345e-7f;     // 2*pi*L^2
    const float Bc = 7.8956835208714865e-7f;     // 2*pi^2*L^2
    #pragma unroll
    for (int it = 0; it < NR; ++it) {
        const int i = rb + it, j = tid;
        float fi = (float)(((i+64)&127) - 64) * DF;
        float fj = (float)(((j+64)&127) - 64) * DF;
        float G  = sqrtf(Ac * expf(-Bc * (fi*fi + fj*fj)) + 1e-12f);
        float2 cv = ((const float2*)c_noise)[(size_t)m*16384 + i*128 + j];
        fld[it*LDSP + j] = { cv.x * G, cv.y * G };
    }
    __syncthreads();

    fft128_rows(fld, tw, tid);

    // transposed fp16 store: thread = column c; 16 rows = 64 B = 4 x uint4
    const int c = tid;
    uint4* dst4 = (uint4*)(mid + (size_t)m*16384 + (size_t)c*128 + rb);
    #pragma unroll
    for (int q = 0; q < 4; ++q) {
        uint4 pk;
        cplx v0 = fld[(4*q+0)*LDSP + c];
        cplx v1 = fld[(4*q+1)*LDSP + c];
        cplx v2 = fld[(4*q+2)*LDSP + c];
        cplx v3 = fld[(4*q+3)*LDSP + c];
        pk.x = h2_to_u(__floats2half2_rn(v0.x, v0.y));
        pk.y = h2_to_u(__floats2half2_rn(v1.x, v1.y));
        pk.z = h2_to_u(__floats2half2_rn(v2.x, v2.y));
        pk.w = h2_to_u(__floats2half2_rn(v3.x, v3.y));
        dst4[q] = pk;
    }
}

// K2: 2 screens concurrently (128-thread sub-groups); col FFT; |T|^2 in
// place; slab-sum + lane-coalesced atomicAdd into shifted Wsh.
__global__ __launch_bounds__(256)
void colfft_acc_kernel(const __half2* __restrict__ mid,
                       float* __restrict__ Wsh, int M)
{
    __shared__ cplx fld[MG * NR * LDSP];      // 2 slabs of 16 rows -> 33.3 KB
    __shared__ cplx tw[128];
    const int g   = blockIdx.x;               // screen pair
    const int cb  = blockIdx.y * NR;          // column tile base (16-aligned)
    const int tid = threadIdx.x;
    const int grp = tid >> 7;                 // screen sub-group 0..1
    const int lt  = tid & 127;                // lane within sub-group

    if (tid < 128) {
        float s, c;
        sincosf((float)tid * (float)(2.0 * M_PI / 128.0), &s, &c);
        tw[tid] = { c, s };
    }

    // load: sub-group grp loads screen m's 16-column tile (fp16 -> f32)
    {
        const int m = g*MG + grp;             // M % MG == 0
        #pragma unroll
        for (int it = 0; it < NR; ++it) {
            float2 v = __half22float2(mid[(size_t)m*16384 + (size_t)(cb + it)*128 + lt]);
            fld[(grp*NR + it)*LDSP + lt] = { v.x, v.y };
        }
    }
    __syncthreads();

    fft128_rows(fld, tw, tid);                // 32 rows across both slabs

    // |T|^2 in place (as .x): fld[it][lt] = |T2d[row lt][col cb+it]|^2
    #pragma unroll
    for (int it = 0; it < NR; ++it) {
        cplx v = fld[(grp*NR + it)*LDSP + lt];
        fld[(grp*NR + it)*LDSP + lt].x = v.x*v.x + v.y*v.y;
    }
    __syncthreads();

    // lane-coalesced accumulate into shifted W: value (it, lt2) goes to
    // Wsh[(lt2^64)*128 + (cb^64) + it]. tid-consecutive -> it fastest ->
    // 16 consecutive floats per 16-lane group (full 64B lines).
    const int c0 = cb ^ 64;
    #pragma unroll
    for (int k = 0; k < 8; ++k) {
        int v   = k*256 + tid;                // 0..2047
        int lt2 = v >> 4, it = v & 15;
        float wv = fld[(       it)*LDSP + lt2].x
                 + fld[(NR  +  it)*LDSP + lt2].x;
        atomicAdd(&Wsh[((lt2 ^ 64) << 7) + c0 + it], wv);
    }
}

// K3: out[b] = (1/M) * sum_p x[b,p]^2 * Wsh[p]. 1024 threads (16 waves)
// per batch-block: 4x the outstanding loads vs 256-thread version; x[b]
// (64KB) + Wsh (64KB, shared) are L2-hot.
__global__ __launch_bounds__(1024)
void dot_kernel(const float* __restrict__ x, const float* __restrict__ Wsh,
                float* __restrict__ out, int M)
{
    const int b = blockIdx.x;
    const float4* x4 = (const float4*)(x + (size_t)b * 16384);
    const float4* w4 = (const float4*)Wsh;
    float acc = 0.f;
    #pragma unroll
    for (int k = threadIdx.x; k < 4096; k += 1024) {
        float4 xv = x4[k], wv = w4[k];
        acc = fmaf(xv.x*xv.x, wv.x, acc);
        acc = fmaf(xv.y*xv.y, wv.y, acc);
        acc = fmaf(xv.z*xv.z, wv.z, acc);
        acc = fmaf(xv.w*xv.w, wv.w, acc);
    }
    #pragma unroll
    for (int off = 32; off > 0; off >>= 1) acc += __shfl_down(acc, off);
    __shared__ float part[16];
    if ((threadIdx.x & 63) == 0) part[threadIdx.x >> 6] = acc;
    __syncthreads();
    if (threadIdx.x == 0) {
        float s = 0.f;
        #pragma unroll
        for (int w = 0; w < 16; ++w) s += part[w];
        out[b] = s / (float)M;
    }
}

extern "C" void kernel_launch(void* const* d_in, const int* in_sizes, int n_in,
                              void* d_out, int out_size, void* d_ws, size_t ws_size,
                              hipStream_t stream)
{
    (void)n_in; (void)ws_size;
    const float* x_in    = (const float*)d_in[0];
    // d_in[1] (phases) provably does not affect the output (|exp(i*phase)|=1).
    const float* c_noise = (const float*)d_in[2];

    const int M = in_sizes[2] / (128*128*2);   // 100 (M % MG == 0)
    const int B = out_size;                    // 32

    __half2* mid = (__half2*)d_ws;                                   // 6.55 MB
    float*   Wsh = (float*)((char*)d_ws + (size_t)M*16384*sizeof(__half2)); // 64 KB

    const int G = M / MG;                      // 50 screen pairs

    rowfft_kernel    <<<dim3(M, 8), dim3(128),  0, stream>>>(c_noise, mid, Wsh);
    colfft_acc_kernel<<<dim3(G, 8), dim3(256),  0, stream>>>(mid, Wsh, M);
    dot_kernel       <<<dim3(B),    dim3(1024), 0, stream>>>(x_in, Wsh,
                                                             (float*)d_out, M);
}

// Round 16
// 21.952 us; speedup vs baseline: 1.2738x; 1.0394x over previous
//
#include <hip/hip_runtime.h>
#include <hip/hip_fp16.h>

// ============================================================================
// PC-DONN collapse (validated rounds 1-15, absmax 0.0):
//   |H|==1 and |exp(i*phase)|==1; FFT pairs obey Parseval => sum|field|^2 is
//   exactly invariant through the whole propagation chain. Hence
//       out[b] = (1/M) * sum_p x_in[b,p]^2 * sum_m |T_m[p]|^2
//   with T_m = fftshift(IDFT2_unnorm(C_m * G)), G = sqrt(p_v + 1e-12).
//
// Round 16: R15 = 22.8us (K3-widening prediction hit). Structure is the
// validated optimum {K1 rowFFT->fp16 mid, K2 colFFT+scattered atomics,
// K3 wide dot}. Remaining above-floor: the two FFT kernels' memory paths.
//  (1) K1: float4 c_noise loads (16->8 load instrs/thread, 16B/lane) and
//      factorized Gaussian G^2 = Ac*efi[i]*efj[j] + 1e-12 via two small
//      LDS tables -- kills 15 of 16 expf per thread (product-of-exps vs
//      exp-of-sum differs ~1e-7 rel, << fp16 mid noise already validated).
//  (2) K2: uint4 mid loads (4B/lane -> 16B/lane, 16->4 load instrs);
//      (row=q&15, ch=q>>4) mapping keeps 16 fully-consumed 64B lines per
//      wave-load and 2-way (free) LDS write conflicts.
// K3 and all layouts byte-identical to R15. Predict 22.8 -> ~20-21.5;
// if within noise, kernels are at latency floor -> roofline next.
// ============================================================================

struct cplx { float x, y; };
__device__ __forceinline__ cplx cadd(cplx a, cplx b){ return {a.x+b.x, a.y+b.y}; }
__device__ __forceinline__ cplx csub(cplx a, cplx b){ return {a.x-b.x, a.y-b.y}; }
__device__ __forceinline__ cplx cmul(cplx a, cplx b){ return {a.x*b.x - a.y*b.y, a.x*b.y + a.y*b.x}; }
__device__ __forceinline__ cplx cmuli(cplx a){ return {-a.y, a.x}; }   // * (+i): inverse-FFT sign

__device__ __forceinline__ void idft4(cplx&A,cplx&B,cplx&C,cplx&D){
    cplx e0=cadd(A,C), e1=csub(A,C), o0=cadd(B,D), o1=csub(B,D);
    cplx i1 = cmuli(o1);
    A=cadd(e0,o0); B=cadd(e1,i1); C=csub(e0,o0); D=csub(e1,i1);
}
__device__ __forceinline__ void idft8(cplx a[8]){
    cplx e0=a[0],e1=a[2],e2=a[4],e3=a[6];
    cplx o0=a[1],o1=a[3],o2=a[5],o3=a[7];
    idft4(e0,e1,e2,e3); idft4(o0,o1,o2,o3);
    const float Ch = 0.70710678118654752f;
    cplx t1 = cmul(o1, cplx{ Ch, Ch});
    cplx t2 = cmuli(o2);
    cplx t3 = cmul(o3, cplx{-Ch, Ch});
    a[0]=cadd(e0,o0); a[4]=csub(e0,o0);
    a[1]=cadd(e1,t1); a[5]=csub(e1,t1);
    a[2]=cadd(e2,t2); a[6]=csub(e2,t2);
    a[3]=cadd(e3,t3); a[7]=csub(e3,t3);
}
__device__ __forceinline__ void idft16(cplx a[16]){
    cplx e[8]={a[0],a[2],a[4],a[6],a[8],a[10],a[12],a[14]};
    cplx o[8]={a[1],a[3],a[5],a[7],a[9],a[11],a[13],a[15]};
    idft8(e); idft8(o);
    const float Ch=0.70710678118654752f, c1=0.92387953251128674f, s1=0.38268343236508977f;
    const cplx w[8]={{1.f,0.f},{c1,s1},{Ch,Ch},{s1,c1},{0.f,1.f},{-s1,c1},{-Ch,Ch},{-c1,s1}};
    #pragma unroll
    for(int n=0;n<8;++n){ cplx t=cmul(o[n],w[n]); a[n]=cadd(e[n],t); a[n+8]=csub(e[n],t); }
}

#define LDSP 130   // padded row stride (cplx)
#define NR   16    // rows (or cols) per tile
#define MG   2     // screens per K2 block (concurrent sub-groups; M%MG==0)

// In-place FFT-128 of (blockDim.x/8) rows in fld. r=tid>>3 row, t=tid&7.
__device__ __forceinline__ void fft128_rows(cplx* fld, const cplx* tw, int tid)
{
    const int r = tid >> 3, t = tid & 7;
    cplx* row = fld + r * LDSP;
    {   cplx a[16];
        #pragma unroll
        for (int k1 = 0; k1 < 16; ++k1) a[k1] = row[t + 8*k1];
        idft16(a);
        #pragma unroll
        for (int n1 = 0; n1 < 16; ++n1) row[t + 8*n1] = cmul(a[n1], tw[(n1*t) & 127]);
    }
    __syncthreads();
    {   cplx b0[8], b1[8];
        #pragma unroll
        for (int k2 = 0; k2 < 8; ++k2) { b0[k2] = row[8*t + k2]; b1[k2] = row[8*(t+8) + k2]; }
        idft8(b0); idft8(b1);
        __syncthreads();
        #pragma unroll
        for (int n2 = 0; n2 < 8; ++n2) {
            row[ t      + 16*n2] = b0[n2];
            row[(t + 8) + 16*n2] = b1[n2];
        }
    }
    __syncthreads();
}

__device__ __forceinline__ unsigned h2_to_u(__half2 h){
    union { __half2 h; unsigned u; } v; v.h = h; return v.u;
}
__device__ __forceinline__ __half2 u_to_h2(unsigned u){
    union { unsigned u; __half2 h; } v; v.u = u; return v.h;
}

// K1: row FFTs of C*G -> transposed fp16 mid[m][c*128 + i]; m==0 blocks
// also zero Wsh (replay-safe accumulation base).
// G factorized: G(i,j) = sqrt(Ac*efi[i]*efj[j] + 1e-12); float4 loads.
__global__ __launch_bounds__(128)
void rowfft_kernel(const float* __restrict__ c_noise, __half2* __restrict__ mid,
                   float* __restrict__ Wsh)
{
    __shared__ cplx  fld[NR * LDSP];
    __shared__ cplx  tw[128];
    __shared__ float efi[NR];
    __shared__ float efj[128];
    const int m   = blockIdx.x;
    const int rb  = blockIdx.y * NR;
    const int tid = threadIdx.x;

    if (m == 0) {                       // zero Wsh: 8 blocks x 2048 floats
        float4* wz = (float4*)Wsh;
        #pragma unroll
        for (int k = 0; k < 4; ++k)
            wz[blockIdx.y*512 + k*128 + tid] = {0.f, 0.f, 0.f, 0.f};
    }

    const float DF = 976.5625f;                  // 1/(N*DX)
    const float Bc = 7.8956835208714865e-7f;     // 2*pi^2*L^2
    {   float s, c;
        sincosf((float)tid * (float)(2.0 * M_PI / 128.0), &s, &c);
        tw[tid] = { c, s };
        float fj = (float)(((tid+64)&127) - 64) * DF;
        efj[tid] = expf(-Bc * fj * fj);
        if (tid < NR) {
            int i = rb + tid;
            float fi = (float)(((i+64)&127) - 64) * DF;
            efi[tid] = expf(-Bc * fi * fi);
        }
    }
    __syncthreads();

    // float4 loads: p = it*128+tid in [0,1024); row r=p>>6, col pair (p&63)*2
    const float Ac = 2.5132741228718345e-7f;     // 2*pi*L^2
    const float4* src = (const float4*)(c_noise + (size_t)m*32768 + (size_t)rb*256);
    #pragma unroll
    for (int it = 0; it < 8; ++it) {
        const int p = it*128 + tid;
        const int r = p >> 6, c2 = (p & 63) << 1;
        float4 v = src[p];
        const float ai = Ac * efi[r];
        float G0 = sqrtf(fmaf(ai, efj[c2  ], 1e-12f));
        float G1 = sqrtf(fmaf(ai, efj[c2+1], 1e-12f));
        fld[r*LDSP + c2    ] = { v.x*G0, v.y*G0 };
        fld[r*LDSP + c2 + 1] = { v.z*G1, v.w*G1 };
    }
    __syncthreads();

    fft128_rows(fld, tw, tid);

    // transposed fp16 store: thread = column c; 16 rows = 64 B = 4 x uint4
    const int c = tid;
    uint4* dst4 = (uint4*)(mid + (size_t)m*16384 + (size_t)c*128 + rb);
    #pragma unroll
    for (int q = 0; q < 4; ++q) {
        uint4 pk;
        cplx v0 = fld[(4*q+0)*LDSP + c];
        cplx v1 = fld[(4*q+1)*LDSP + c];
        cplx v2 = fld[(4*q+2)*LDSP + c];
        cplx v3 = fld[(4*q+3)*LDSP + c];
        pk.x = h2_to_u(__floats2half2_rn(v0.x, v0.y));
        pk.y = h2_to_u(__floats2half2_rn(v1.x, v1.y));
        pk.z = h2_to_u(__floats2half2_rn(v2.x, v2.y));
        pk.w = h2_to_u(__floats2half2_rn(v3.x, v3.y));
        dst4[q] = pk;
    }
}

// K2: 2 screens concurrently (128-thread sub-groups); col FFT; |T|^2 in
// place; slab-sum + lane-coalesced atomicAdd into shifted Wsh.
// uint4 mid loads (16B/lane): q=(row=q&15, ch=q>>4) -> 16 full 64B lines
// per wave-load; LDS writes 2-way (free).
__global__ __launch_bounds__(256)
void colfft_acc_kernel(const __half2* __restrict__ mid,
                       float* __restrict__ Wsh, int M)
{
    __shared__ cplx fld[MG * NR * LDSP];      // 2 slabs of 16 rows -> 33.3 KB
    __shared__ cplx tw[128];
    const int g   = blockIdx.x;               // screen pair
    const int cb  = blockIdx.y * NR;          // column tile base (16-aligned)
    const int tid = threadIdx.x;
    const int grp = tid >> 7;                 // screen sub-group 0..1
    const int lt  = tid & 127;                // lane within sub-group

    if (tid < 128) {
        float s, c;
        sincosf((float)tid * (float)(2.0 * M_PI / 128.0), &s, &c);
        tw[tid] = { c, s };
    }

    // load: sub-group grp loads screen m's 16-column tile as uint4
    {
        const int m = g*MG + grp;             // M % MG == 0
        const uint4* srcm = (const uint4*)(mid + (size_t)m*16384 + (size_t)cb*128);
        #pragma unroll
        for (int it2 = 0; it2 < 4; ++it2) {
            const int q   = it2*128 + lt;     // 0..511
            const int row = q & 15, ch = q >> 4;   // ch 0..31
            uint4 v = srcm[row*32 + ch];
            cplx* dst = &fld[(grp*NR + row)*LDSP + ch*4];
            float2 f0 = __half22float2(u_to_h2(v.x));
            float2 f1 = __half22float2(u_to_h2(v.y));
            float2 f2 = __half22float2(u_to_h2(v.z));
            float2 f3 = __half22float2(u_to_h2(v.w));
            dst[0] = { f0.x, f0.y };
            dst[1] = { f1.x, f1.y };
            dst[2] = { f2.x, f2.y };
            dst[3] = { f3.x, f3.y };
        }
    }
    __syncthreads();

    fft128_rows(fld, tw, tid);                // 32 rows across both slabs

    // |T|^2 in place (as .x): fld[it][lt] = |T2d[row lt][col cb+it]|^2
    #pragma unroll
    for (int it = 0; it < NR; ++it) {
        cplx v = fld[(grp*NR + it)*LDSP + lt];
        fld[(grp*NR + it)*LDSP + lt].x = v.x*v.x + v.y*v.y;
    }
    __syncthreads();

    // lane-coalesced accumulate into shifted W: value (it, lt2) goes to
    // Wsh[(lt2^64)*128 + (cb^64) + it]. tid-consecutive -> it fastest ->
    // 16 consecutive floats per 16-lane group (full 64B lines).
    const int c0 = cb ^ 64;
    #pragma unroll
    for (int k = 0; k < 8; ++k) {
        int v   = k*256 + tid;                // 0..2047
        int lt2 = v >> 4, it = v & 15;
        float wv = fld[(       it)*LDSP + lt2].x
                 + fld[(NR  +  it)*LDSP + lt2].x;
        atomicAdd(&Wsh[((lt2 ^ 64) << 7) + c0 + it], wv);
    }
}

// K3: out[b] = (1/M) * sum_p x[b,p]^2 * Wsh[p]. 1024 threads (16 waves)
// per batch-block; x[b] (64KB) + Wsh (64KB, shared) are L2-hot.
__global__ __launch_bounds__(1024)
void dot_kernel(const float* __restrict__ x, const float* __restrict__ Wsh,
                float* __restrict__ out, int M)
{
    const int b = blockIdx.x;
    const float4* x4 = (const float4*)(x + (size_t)b * 16384);
    const float4* w4 = (const float4*)Wsh;
    float acc = 0.f;
    #pragma unroll
    for (int k = threadIdx.x; k < 4096; k += 1024) {
        float4 xv = x4[k], wv = w4[k];
        acc = fmaf(xv.x*xv.x, wv.x, acc);
        acc = fmaf(xv.y*xv.y, wv.y, acc);
        acc = fmaf(xv.z*xv.z, wv.z, acc);
        acc = fmaf(xv.w*xv.w, wv.w, acc);
    }
    #pragma unroll
    for (int off = 32; off > 0; off >>= 1) acc += __shfl_down(acc, off);
    __shared__ float part[16];
    if ((threadIdx.x & 63) == 0) part[threadIdx.x >> 6] = acc;
    __syncthreads();
    if (threadIdx.x == 0) {
        float s = 0.f;
        #pragma unroll
        for (int w = 0; w < 16; ++w) s += part[w];
        out[b] = s / (float)M;
    }
}

extern "C" void kernel_launch(void* const* d_in, const int* in_sizes, int n_in,
                              void* d_out, int out_size, void* d_ws, size_t ws_size,
                              hipStream_t stream)
{
    (void)n_in; (void)ws_size;
    const float* x_in    = (const float*)d_in[0];
    // d_in[1] (phases) provably does not affect the output (|exp(i*phase)|=1).
    const float* c_noise = (const float*)d_in[2];

    const int M = in_sizes[2] / (128*128*2);   // 100 (M % MG == 0)
    const int B = out_size;                    // 32

    __half2* mid = (__half2*)d_ws;                                   // 6.55 MB
    float*   Wsh = (float*)((char*)d_ws + (size_t)M*16384*sizeof(__half2)); // 64 KB

    const int G = M / MG;                      // 50 screen pairs

    rowfft_kernel    <<<dim3(M, 8), dim3(128),  0, stream>>>(c_noise, mid, Wsh);
    colfft_acc_kernel<<<dim3(G, 8), dim3(256),  0, stream>>>(mid, Wsh, M);
    dot_kernel       <<<dim3(B),    dim3(1024), 0, stream>>>(x_in, Wsh,
                                                             (float*)d_out, M);
}